// Round 1
// baseline (5758.672 us; speedup 1.0000x reference)
//
#include <hip/hip_runtime.h>

#define HH 128
#define LN_EPS 1e-5f

// ---------------------------------------------------------------------------
// Detect edge_index layout: int64 (odd 32-bit words all zero) vs int32.
__global__ __launch_bounds__(64) void k_detect(const int* __restrict__ ei, int* __restrict__ flag) {
    if (threadIdx.x == 0) {
        int all0 = 1;
        for (int i = 1; i < 128; i += 2) all0 &= (ei[i] == 0);
        *flag = all0;   // 1 -> int64, 0 -> int32
    }
}

// ---------------------------------------------------------------------------
// Per-edge MLPs: vx = 1/(mlpx(ea)+1e-6), vz = mlpz(ea)+1e-6
__global__ __launch_bounds__(256) void k_edge_mlp(
    const float* __restrict__ ea,
    const float* __restrict__ xw1, const float* __restrict__ xb1,
    const float* __restrict__ xw2, const float* __restrict__ xb2,
    const float* __restrict__ zw1, const float* __restrict__ zb1,
    const float* __restrict__ zw2, const float* __restrict__ zb2,
    float* __restrict__ vx, float* __restrict__ vz, int E)
{
    int e = blockIdx.x * 256 + threadIdx.x;
    if (e >= E) return;
    float4 t0 = *(const float4*)&ea[(size_t)e * 8];
    float4 t1 = *(const float4*)&ea[(size_t)e * 8 + 4];
    float a[8] = {t0.x, t0.y, t0.z, t0.w, t1.x, t1.y, t1.z, t1.w};
    float sx = 0.f, sz = 0.f;
#pragma unroll
    for (int j = 0; j < 16; ++j) {
        float hx = xb1[j], hz = zb1[j];
#pragma unroll
        for (int i = 0; i < 8; ++i) {
            hx += a[i] * xw1[i * 16 + j];
            hz += a[i] * zw1[i * 16 + j];
        }
        sx += tanhf(hx) * xw2[j];
        sz += tanhf(hz) * zw2[j];
    }
    sx += xb2[0];
    sz += zb2[0];
    vx[e] = 1.0f / (sx + 1e-6f);
    vz[e] = sz + 1e-6f;
}

// ---------------------------------------------------------------------------
// GEMM: out-tile = A[64 rows] @ W (128x128), W staged in LDS.
// MODE 0: out = (A@W)^2          (uw2)
// MODE 1: azt = A@W; y = silu(LN(azt))+1e-6; d_out = clip(u - 0.1*(first + dg*y))
template <int MODE>
__global__ __launch_bounds__(256) void k_gemm(
    const float* __restrict__ A, const float* __restrict__ W,
    float* __restrict__ out,
    const float* __restrict__ u, const float* __restrict__ first,
    const float* __restrict__ g, const float* __restrict__ bb,
    const float* __restrict__ dgp, int N)
{
    __shared__ float wl[HH * HH];   // 64 KiB
    int tid = threadIdx.x;
    for (int i = tid; i < HH * HH / 4; i += 256)
        ((float4*)wl)[i] = ((const float4*)W)[i];
    __syncthreads();

    int rg = tid >> 4, cg = tid & 15;
    int r0 = blockIdx.x * 64 + rg * 4;

    float acc[4][8];
#pragma unroll
    for (int rr = 0; rr < 4; ++rr)
#pragma unroll
        for (int j = 0; j < 8; ++j) acc[rr][j] = 0.f;

    size_t rowidx[4];
#pragma unroll
    for (int rr = 0; rr < 4; ++rr) {
        int r = r0 + rr;
        rowidx[rr] = (size_t)(r < N - 1 ? r : N - 1) * HH;
    }

    for (int k4 = 0; k4 < 32; ++k4) {
        float4 a4[4];
#pragma unroll
        for (int rr = 0; rr < 4; ++rr)
            a4[rr] = *(const float4*)&A[rowidx[rr] + k4 * 4];
#pragma unroll
        for (int kk = 0; kk < 4; ++kk) {
            int k = k4 * 4 + kk;
            float4 w0 = *(const float4*)&wl[k * HH + cg * 4];
            float4 w1 = *(const float4*)&wl[k * HH + 64 + cg * 4];
#pragma unroll
            for (int rr = 0; rr < 4; ++rr) {
                float av = ((const float*)&a4[rr])[kk];
                acc[rr][0] += av * w0.x; acc[rr][1] += av * w0.y;
                acc[rr][2] += av * w0.z; acc[rr][3] += av * w0.w;
                acc[rr][4] += av * w1.x; acc[rr][5] += av * w1.y;
                acc[rr][6] += av * w1.z; acc[rr][7] += av * w1.w;
            }
        }
    }

    if (MODE == 0) {
#pragma unroll
        for (int rr = 0; rr < 4; ++rr) {
            int r = r0 + rr;
            if (r >= N) continue;
            float4 o0, o1;
            o0.x = acc[rr][0] * acc[rr][0]; o0.y = acc[rr][1] * acc[rr][1];
            o0.z = acc[rr][2] * acc[rr][2]; o0.w = acc[rr][3] * acc[rr][3];
            o1.x = acc[rr][4] * acc[rr][4]; o1.y = acc[rr][5] * acc[rr][5];
            o1.z = acc[rr][6] * acc[rr][6]; o1.w = acc[rr][7] * acc[rr][7];
            *(float4*)&out[(size_t)r * HH + cg * 4] = o0;
            *(float4*)&out[(size_t)r * HH + 64 + cg * 4] = o1;
        }
    } else {
        float dg = *dgp;
        float4 gv0 = *(const float4*)&g[cg * 4];
        float4 gv1 = *(const float4*)&g[64 + cg * 4];
        float4 bv0 = *(const float4*)&bb[cg * 4];
        float4 bv1 = *(const float4*)&bb[64 + cg * 4];
        float gA[8] = {gv0.x, gv0.y, gv0.z, gv0.w, gv1.x, gv1.y, gv1.z, gv1.w};
        float bA[8] = {bv0.x, bv0.y, bv0.z, bv0.w, bv1.x, bv1.y, bv1.z, bv1.w};
#pragma unroll
        for (int rr = 0; rr < 4; ++rr) {
            int r = r0 + rr;
            // row mean across 16 lanes (each holds 8 of 128 cols)
            float s = 0.f;
#pragma unroll
            for (int j = 0; j < 8; ++j) s += acc[rr][j];
            s += __shfl_xor(s, 1, 16);
            s += __shfl_xor(s, 2, 16);
            s += __shfl_xor(s, 4, 16);
            s += __shfl_xor(s, 8, 16);
            float mu = s * (1.f / 128.f);
            float xc[8], s2 = 0.f;
#pragma unroll
            for (int j = 0; j < 8; ++j) { xc[j] = acc[rr][j] - mu; s2 += xc[j] * xc[j]; }
            s2 += __shfl_xor(s2, 1, 16);
            s2 += __shfl_xor(s2, 2, 16);
            s2 += __shfl_xor(s2, 4, 16);
            s2 += __shfl_xor(s2, 8, 16);
            float rs = rsqrtf(s2 * (1.f / 128.f) + LN_EPS);
            float y[8];
#pragma unroll
            for (int j = 0; j < 8; ++j) {
                float v = xc[j] * rs * gA[j] + bA[j];
                v = v / (1.f + expf(-v));   // silu
                y[j] = v + 1e-6f;
            }
            if (r < N) {
                size_t b0 = (size_t)r * HH + cg * 4;
                size_t b1 = (size_t)r * HH + 64 + cg * 4;
                float4 u0 = *(const float4*)&u[b0];
                float4 u1 = *(const float4*)&u[b1];
                float4 f0 = *(const float4*)&first[b0];
                float4 f1 = *(const float4*)&first[b1];
                float4 o0, o1;
                o0.x = u0.x - 0.1f * (f0.x + dg * y[0]);
                o0.y = u0.y - 0.1f * (f0.y + dg * y[1]);
                o0.z = u0.z - 0.1f * (f0.z + dg * y[2]);
                o0.w = u0.w - 0.1f * (f0.w + dg * y[3]);
                o1.x = u1.x - 0.1f * (f1.x + dg * y[4]);
                o1.y = u1.y - 0.1f * (f1.y + dg * y[5]);
                o1.z = u1.z - 0.1f * (f1.z + dg * y[6]);
                o1.w = u1.w - 0.1f * (f1.w + dg * y[7]);
                o0.x = fminf(fmaxf(o0.x, -10.f), 10.f);
                o0.y = fminf(fmaxf(o0.y, -10.f), 10.f);
                o0.z = fminf(fmaxf(o0.z, -10.f), 10.f);
                o0.w = fminf(fmaxf(o0.w, -10.f), 10.f);
                o1.x = fminf(fmaxf(o1.x, -10.f), 10.f);
                o1.y = fminf(fmaxf(o1.y, -10.f), 10.f);
                o1.z = fminf(fmaxf(o1.z, -10.f), 10.f);
                o1.w = fminf(fmaxf(o1.w, -10.f), 10.f);
                *(float4*)&out[b0] = o0;
                *(float4*)&out[b1] = o1;
            }
        }
    }
}

// ---------------------------------------------------------------------------
// Fused scatter for both spmm_diffs. 32 threads per edge (4 cols each).
__global__ __launch_bounds__(256) void k_scatter(
    const int* __restrict__ ei, const int* __restrict__ flag,
    const float* __restrict__ vx, const float* __restrict__ vz,
    const float* __restrict__ uw2, const float* __restrict__ u,
    float* __restrict__ acc1, float* __restrict__ acc2,
    float* __restrict__ d1, float* __restrict__ d2, int E)
{
    long long t = (long long)blockIdx.x * 256 + threadIdx.x;
    int e = (int)(t >> 5);
    if (e >= E) return;
    int q = (int)(t & 31);
    int f64 = *flag;
    int r, c;
    if (f64) {
        r = ei[2 * (size_t)e];
        c = ei[2 * ((size_t)E + e)];
    } else {
        r = ei[e];
        c = ei[(size_t)E + e];
    }
    float fx = vx[e], fz = vz[e];
    size_t rb = (size_t)r * HH + q * 4;
    size_t cb = (size_t)c * HH + q * 4;
    float4 a = *(const float4*)&uw2[rb];
    float4 bu = *(const float4*)&u[rb];
    atomicAdd(&acc1[cb + 0], fx * a.x);
    atomicAdd(&acc1[cb + 1], fx * a.y);
    atomicAdd(&acc1[cb + 2], fx * a.z);
    atomicAdd(&acc1[cb + 3], fx * a.w);
    atomicAdd(&acc2[cb + 0], fz * bu.x);
    atomicAdd(&acc2[cb + 1], fz * bu.y);
    atomicAdd(&acc2[cb + 2], fz * bu.z);
    atomicAdd(&acc2[cb + 3], fz * bu.w);
    if (q == 0) {
        atomicAdd(&d1[c], fx);
        atomicAdd(&d2[c], fz);
    }
}

// ---------------------------------------------------------------------------
// Per-node finish: first = silu(LN(d1'*uw2 + acc1)) (into acc1, in place);
//                  az    = d2'*u + acc2              (into acc2, in place)
__global__ __launch_bounds__(256) void k_node(
    const float* __restrict__ uw2, const float* __restrict__ u,
    float* __restrict__ acc1, float* __restrict__ acc2,
    const float* __restrict__ d1, const float* __restrict__ d2,
    const float* __restrict__ g1, const float* __restrict__ b1,
    int N)
{
    int wave = threadIdx.x >> 6, lane = threadIdx.x & 63;
    int node = blockIdx.x * 4 + wave;
    if (node >= N) return;
    size_t base = (size_t)node * HH + lane * 2;
    float2 a1 = *(const float2*)&acc1[base];
    float2 w2 = *(const float2*)&uw2[base];
    float d = d1[node];
    if (d == 0.f) d = 1.f;
    float x0 = d * w2.x + a1.x;
    float x1 = d * w2.y + a1.y;
    float s = x0 + x1;
#pragma unroll
    for (int m = 1; m < 64; m <<= 1) s += __shfl_xor(s, m, 64);
    float mu = s * (1.f / 128.f);
    float c0 = x0 - mu, c1 = x1 - mu;
    float s2 = c0 * c0 + c1 * c1;
#pragma unroll
    for (int m = 1; m < 64; m <<= 1) s2 += __shfl_xor(s2, m, 64);
    float rs = rsqrtf(s2 * (1.f / 128.f) + LN_EPS);
    float y0 = c0 * rs * g1[lane * 2] + b1[lane * 2];
    float y1 = c1 * rs * g1[lane * 2 + 1] + b1[lane * 2 + 1];
    y0 = y0 / (1.f + expf(-y0));
    y1 = y1 / (1.f + expf(-y1));
    *(float2*)&acc1[base] = make_float2(y0, y1);

    float2 uu = *(const float2*)&u[base];
    float2 a2 = *(const float2*)&acc2[base];
    float dz = d2[node];
    if (dz == 0.f) dz = 1.f;
    *(float2*)&acc2[base] = make_float2(dz * uu.x + a2.x, dz * uu.y + a2.y);
}

// ---------------------------------------------------------------------------
extern "C" void kernel_launch(void* const* d_in, const int* in_sizes, int n_in,
                              void* d_out, int out_size, void* d_ws, size_t ws_size,
                              hipStream_t stream)
{
    const float* u   = (const float*)d_in[0];
    const int*   ei  = (const int*)d_in[1];
    const float* ea  = (const float*)d_in[2];
    const float* xw1 = (const float*)d_in[4];
    const float* xb1 = (const float*)d_in[5];
    const float* xw2 = (const float*)d_in[6];
    const float* xb2 = (const float*)d_in[7];
    const float* zw1 = (const float*)d_in[8];
    const float* zb1 = (const float*)d_in[9];
    const float* zw2 = (const float*)d_in[10];
    const float* zb2 = (const float*)d_in[11];
    const float* weight = (const float*)d_in[12];
    const float* azw = (const float*)d_in[13];
    const float* n1g = (const float*)d_in[14];
    const float* n1b = (const float*)d_in[15];
    const float* n2g = (const float*)d_in[16];
    const float* n2b = (const float*)d_in[17];
    const float* dgp = (const float*)d_in[18];

    int N = in_sizes[0] / HH;
    int E = in_sizes[2] / 8;
    size_t NH = (size_t)N * HH;

    float* vx   = (float*)d_ws;
    float* vz   = vx + E;
    float* uw2  = vz + E;
    float* acc1 = uw2 + NH;
    float* acc2 = acc1 + NH;
    float* d1   = acc2 + NH;
    float* d2   = d1 + N;
    int*   flag = (int*)(d2 + N);
    float* out  = (float*)d_out;

    // zero acc1, acc2, d1, d2 (contiguous)
    (void)hipMemsetAsync(acc1, 0, (2 * NH + 2 * (size_t)N) * sizeof(float), stream);

    k_detect<<<1, 64, 0, stream>>>(ei, flag);

    k_edge_mlp<<<(E + 255) / 256, 256, 0, stream>>>(
        ea, xw1, xb1, xw2, xb2, zw1, zb1, zw2, zb2, vx, vz, E);

    k_gemm<0><<<(N + 63) / 64, 256, 0, stream>>>(
        u, weight, uw2, nullptr, nullptr, nullptr, nullptr, nullptr, N);

    long long tot = (long long)E * 32;
    k_scatter<<<(int)((tot + 255) / 256), 256, 0, stream>>>(
        ei, flag, vx, vz, uw2, u, acc1, acc2, d1, d2, E);

    k_node<<<(N + 3) / 4, 256, 0, stream>>>(
        uw2, u, acc1, acc2, d1, d2, n1g, n1b, N);

    k_gemm<1><<<(N + 63) / 64, 256, 0, stream>>>(
        acc2, azw, out, u, acc1, n2g, n2b, dgp, N);
}

// Round 2
// 573.605 us; speedup vs baseline: 10.0394x; 10.0394x over previous
//
#include <hip/hip_runtime.h>

#define HH 128
#define LN_EPS 1e-5f

// ---------------------------------------------------------------------------
// Detect edge_index layout: int64 (odd 32-bit words all zero) vs int32.
__global__ __launch_bounds__(64) void k_detect(const int* __restrict__ ei, int* __restrict__ flag) {
    if (threadIdx.x == 0) {
        int all0 = 1;
        for (int i = 1; i < 128; i += 2) all0 &= (ei[i] == 0);
        *flag = all0;   // 1 -> int64, 0 -> int32
    }
}

// ---------------------------------------------------------------------------
// Histogram of destination column counts.
__global__ __launch_bounds__(256) void k_hist(
    const int* __restrict__ ei, const int* __restrict__ flag,
    int* __restrict__ cnt, int E)
{
    int e = blockIdx.x * 256 + threadIdx.x;
    if (e >= E) return;
    int c = (*flag) ? ei[2 * ((size_t)E + e)] : ei[(size_t)E + e];
    atomicAdd(&cnt[c], 1);
}

// ---------------------------------------------------------------------------
// Scan stage A: per-block (1024 elements) exclusive scan + block sums.
__global__ __launch_bounds__(256) void k_scan_a(
    const int* __restrict__ cnt, int* __restrict__ off,
    int* __restrict__ bs, int N)
{
    __shared__ int sm[256];
    int tid = threadIdx.x;
    int base = blockIdx.x * 1024 + tid * 4;
    int v0 = base + 0 < N ? cnt[base + 0] : 0;
    int v1 = base + 1 < N ? cnt[base + 1] : 0;
    int v2 = base + 2 < N ? cnt[base + 2] : 0;
    int v3 = base + 3 < N ? cnt[base + 3] : 0;
    int s = v0 + v1 + v2 + v3;
    sm[tid] = s;
    __syncthreads();
    for (int o = 1; o < 256; o <<= 1) {
        int t = (tid >= o) ? sm[tid - o] : 0;
        __syncthreads();
        sm[tid] += t;
        __syncthreads();
    }
    int excl = sm[tid] - s;
    if (tid == 255) bs[blockIdx.x] = sm[tid];
    if (base + 0 < N) off[base + 0] = excl;
    if (base + 1 < N) off[base + 1] = excl + v0;
    if (base + 2 < N) off[base + 2] = excl + v0 + v1;
    if (base + 3 < N) off[base + 3] = excl + v0 + v1 + v2;
}

// Scan stage B: single-block exclusive scan of block sums.
__global__ __launch_bounds__(256) void k_scan_b(int* __restrict__ bs, int nb)
{
    __shared__ int sm[256];
    int tid = threadIdx.x;
    int s = tid < nb ? bs[tid] : 0;
    sm[tid] = s;
    __syncthreads();
    for (int o = 1; o < 256; o <<= 1) {
        int t = (tid >= o) ? sm[tid - o] : 0;
        __syncthreads();
        sm[tid] += t;
        __syncthreads();
    }
    if (tid < nb) bs[tid] = sm[tid] - s;   // exclusive
}

// Scan stage C: add block bases, produce final offsets + cursor copy.
__global__ __launch_bounds__(256) void k_scan_c(
    int* __restrict__ off, const int* __restrict__ bs,
    int* __restrict__ cursor, int N, int E)
{
    int i = blockIdx.x * 256 + threadIdx.x;
    if (i >= N) return;
    int o = off[i] + bs[i >> 10];
    off[i] = o;
    cursor[i] = o;
    if (i == 0) off[N] = E;
}

// ---------------------------------------------------------------------------
// Per-edge MLPs fused with CSR fill:
//   csr[p] = {row_bits, 1/(mlpx+1e-6), mlpz+1e-6, 0} at p = cursor[col]++
__global__ __launch_bounds__(256) void k_edge_mlp_fill(
    const float* __restrict__ ea,
    const float* __restrict__ xw1, const float* __restrict__ xb1,
    const float* __restrict__ xw2, const float* __restrict__ xb2,
    const float* __restrict__ zw1, const float* __restrict__ zb1,
    const float* __restrict__ zw2, const float* __restrict__ zb2,
    const int* __restrict__ ei, const int* __restrict__ flag,
    int* __restrict__ cursor, float4* __restrict__ csr, int E)
{
    int e = blockIdx.x * 256 + threadIdx.x;
    if (e >= E) return;
    float4 t0 = *(const float4*)&ea[(size_t)e * 8];
    float4 t1 = *(const float4*)&ea[(size_t)e * 8 + 4];
    float a[8] = {t0.x, t0.y, t0.z, t0.w, t1.x, t1.y, t1.z, t1.w};
    float sx = 0.f, sz = 0.f;
#pragma unroll
    for (int j = 0; j < 16; ++j) {
        float hx = xb1[j], hz = zb1[j];
#pragma unroll
        for (int i = 0; i < 8; ++i) {
            hx += a[i] * xw1[i * 16 + j];
            hz += a[i] * zw1[i * 16 + j];
        }
        sx += tanhf(hx) * xw2[j];
        sz += tanhf(hz) * zw2[j];
    }
    sx += xb2[0];
    sz += zb2[0];
    int r, c;
    if (*flag) {
        r = ei[2 * (size_t)e];
        c = ei[2 * ((size_t)E + e)];
    } else {
        r = ei[e];
        c = ei[(size_t)E + e];
    }
    int p = atomicAdd(&cursor[c], 1);
    float4 m;
    m.x = __int_as_float(r);
    m.y = 1.0f / (sx + 1e-6f);
    m.z = sz + 1e-6f;
    m.w = 0.f;
    csr[p] = m;
}

// ---------------------------------------------------------------------------
// GEMM: out-tile = A[64 rows] @ W (128x128), W staged in LDS.
// MODE 0: out = (A@W)^2          (uw2)
// MODE 1: azt = A@W; y = silu(LN(azt))+1e-6; d_out = clip(u - 0.1*(first + dg*y))
//   NOTE: in MODE 1, out and first may alias (both point at d_out).
template <int MODE>
__global__ __launch_bounds__(256) void k_gemm(
    const float* __restrict__ A, const float* __restrict__ W,
    float* out,
    const float* __restrict__ u, const float* first,
    const float* __restrict__ g, const float* __restrict__ bb,
    const float* __restrict__ dgp, int N)
{
    __shared__ float wl[HH * HH];   // 64 KiB
    int tid = threadIdx.x;
    for (int i = tid; i < HH * HH / 4; i += 256)
        ((float4*)wl)[i] = ((const float4*)W)[i];
    __syncthreads();

    int rg = tid >> 4, cg = tid & 15;
    int r0 = blockIdx.x * 64 + rg * 4;

    float acc[4][8];
#pragma unroll
    for (int rr = 0; rr < 4; ++rr)
#pragma unroll
        for (int j = 0; j < 8; ++j) acc[rr][j] = 0.f;

    size_t rowidx[4];
#pragma unroll
    for (int rr = 0; rr < 4; ++rr) {
        int r = r0 + rr;
        rowidx[rr] = (size_t)(r < N - 1 ? r : N - 1) * HH;
    }

    for (int k4 = 0; k4 < 32; ++k4) {
        float4 a4[4];
#pragma unroll
        for (int rr = 0; rr < 4; ++rr)
            a4[rr] = *(const float4*)&A[rowidx[rr] + k4 * 4];
#pragma unroll
        for (int kk = 0; kk < 4; ++kk) {
            int k = k4 * 4 + kk;
            float4 w0 = *(const float4*)&wl[k * HH + cg * 4];
            float4 w1 = *(const float4*)&wl[k * HH + 64 + cg * 4];
#pragma unroll
            for (int rr = 0; rr < 4; ++rr) {
                float av = ((const float*)&a4[rr])[kk];
                acc[rr][0] += av * w0.x; acc[rr][1] += av * w0.y;
                acc[rr][2] += av * w0.z; acc[rr][3] += av * w0.w;
                acc[rr][4] += av * w1.x; acc[rr][5] += av * w1.y;
                acc[rr][6] += av * w1.z; acc[rr][7] += av * w1.w;
            }
        }
    }

    if (MODE == 0) {
#pragma unroll
        for (int rr = 0; rr < 4; ++rr) {
            int r = r0 + rr;
            if (r >= N) continue;
            float4 o0, o1;
            o0.x = acc[rr][0] * acc[rr][0]; o0.y = acc[rr][1] * acc[rr][1];
            o0.z = acc[rr][2] * acc[rr][2]; o0.w = acc[rr][3] * acc[rr][3];
            o1.x = acc[rr][4] * acc[rr][4]; o1.y = acc[rr][5] * acc[rr][5];
            o1.z = acc[rr][6] * acc[rr][6]; o1.w = acc[rr][7] * acc[rr][7];
            *(float4*)&out[(size_t)r * HH + cg * 4] = o0;
            *(float4*)&out[(size_t)r * HH + 64 + cg * 4] = o1;
        }
    } else {
        float dg = *dgp;
        float4 gv0 = *(const float4*)&g[cg * 4];
        float4 gv1 = *(const float4*)&g[64 + cg * 4];
        float4 bv0 = *(const float4*)&bb[cg * 4];
        float4 bv1 = *(const float4*)&bb[64 + cg * 4];
        float gA[8] = {gv0.x, gv0.y, gv0.z, gv0.w, gv1.x, gv1.y, gv1.z, gv1.w};
        float bA[8] = {bv0.x, bv0.y, bv0.z, bv0.w, bv1.x, bv1.y, bv1.z, bv1.w};
#pragma unroll
        for (int rr = 0; rr < 4; ++rr) {
            int r = r0 + rr;
            float s = 0.f;
#pragma unroll
            for (int j = 0; j < 8; ++j) s += acc[rr][j];
            s += __shfl_xor(s, 1, 16);
            s += __shfl_xor(s, 2, 16);
            s += __shfl_xor(s, 4, 16);
            s += __shfl_xor(s, 8, 16);
            float mu = s * (1.f / 128.f);
            float xc[8], s2 = 0.f;
#pragma unroll
            for (int j = 0; j < 8; ++j) { xc[j] = acc[rr][j] - mu; s2 += xc[j] * xc[j]; }
            s2 += __shfl_xor(s2, 1, 16);
            s2 += __shfl_xor(s2, 2, 16);
            s2 += __shfl_xor(s2, 4, 16);
            s2 += __shfl_xor(s2, 8, 16);
            float rs = rsqrtf(s2 * (1.f / 128.f) + LN_EPS);
            float y[8];
#pragma unroll
            for (int j = 0; j < 8; ++j) {
                float v = xc[j] * rs * gA[j] + bA[j];
                v = v / (1.f + expf(-v));   // silu
                y[j] = v + 1e-6f;
            }
            if (r < N) {
                size_t b0 = (size_t)r * HH + cg * 4;
                size_t b1 = (size_t)r * HH + 64 + cg * 4;
                float4 u0 = *(const float4*)&u[b0];
                float4 u1 = *(const float4*)&u[b1];
                float4 f0 = *(const float4*)&first[b0];
                float4 f1 = *(const float4*)&first[b1];
                float4 o0, o1;
                o0.x = u0.x - 0.1f * (f0.x + dg * y[0]);
                o0.y = u0.y - 0.1f * (f0.y + dg * y[1]);
                o0.z = u0.z - 0.1f * (f0.z + dg * y[2]);
                o0.w = u0.w - 0.1f * (f0.w + dg * y[3]);
                o1.x = u1.x - 0.1f * (f1.x + dg * y[4]);
                o1.y = u1.y - 0.1f * (f1.y + dg * y[5]);
                o1.z = u1.z - 0.1f * (f1.z + dg * y[6]);
                o1.w = u1.w - 0.1f * (f1.w + dg * y[7]);
                o0.x = fminf(fmaxf(o0.x, -10.f), 10.f);
                o0.y = fminf(fmaxf(o0.y, -10.f), 10.f);
                o0.z = fminf(fmaxf(o0.z, -10.f), 10.f);
                o0.w = fminf(fmaxf(o0.w, -10.f), 10.f);
                o1.x = fminf(fmaxf(o1.x, -10.f), 10.f);
                o1.y = fminf(fmaxf(o1.y, -10.f), 10.f);
                o1.z = fminf(fmaxf(o1.z, -10.f), 10.f);
                o1.w = fminf(fmaxf(o1.w, -10.f), 10.f);
                *(float4*)&out[b0] = o0;
                *(float4*)&out[b1] = o1;
            }
        }
    }
}

// ---------------------------------------------------------------------------
// Gather: one wave per node. Walk incoming-edge CSR list, accumulate both
// spmm results in registers, then finish:
//   first = silu(LN(d1'*uw2[c] + acc1))  -> written to d_out (scratch reuse)
//   az    = d2'*u[c] + acc2              -> az buffer
__global__ __launch_bounds__(256) void k_gather(
    const float4* __restrict__ csr, const int* __restrict__ off,
    const float* __restrict__ uw2, const float* __restrict__ u,
    const float* __restrict__ g1, const float* __restrict__ b1,
    float* __restrict__ first, float* __restrict__ az, int N)
{
    int wave = threadIdx.x >> 6, lane = threadIdx.x & 63;
    int node = blockIdx.x * 4 + wave;
    if (node >= N) return;
    int p = off[node], end = off[node + 1];

    float a1x = 0.f, a1y = 0.f, a2x = 0.f, a2y = 0.f;
    float dd1 = 0.f, dd2 = 0.f;
    int li = lane * 2;

    float4 m;
    if (p < end) m = csr[p];
    while (p < end) {
        float4 cur = m;
        ++p;
        if (p < end) m = csr[p];              // prefetch next edge meta
        int row = __float_as_int(cur.x);
        size_t rb = (size_t)row * HH + li;
        float2 w2 = *(const float2*)&uw2[rb];
        float2 uu = *(const float2*)&u[rb];
        a1x += cur.y * w2.x; a1y += cur.y * w2.y;
        a2x += cur.z * uu.x; a2y += cur.z * uu.y;
        dd1 += cur.y; dd2 += cur.z;
    }
    if (dd1 == 0.f) dd1 = 1.f;
    if (dd2 == 0.f) dd2 = 1.f;

    size_t base = (size_t)node * HH + li;
    float2 w2c = *(const float2*)&uw2[base];
    float2 uuc = *(const float2*)&u[base];

    float x0 = dd1 * w2c.x + a1x;
    float x1 = dd1 * w2c.y + a1y;
    float s = x0 + x1;
#pragma unroll
    for (int mk = 1; mk < 64; mk <<= 1) s += __shfl_xor(s, mk, 64);
    float mu = s * (1.f / 128.f);
    float c0 = x0 - mu, c1 = x1 - mu;
    float s2 = c0 * c0 + c1 * c1;
#pragma unroll
    for (int mk = 1; mk < 64; mk <<= 1) s2 += __shfl_xor(s2, mk, 64);
    float rs = rsqrtf(s2 * (1.f / 128.f) + LN_EPS);
    float y0 = c0 * rs * g1[li] + b1[li];
    float y1 = c1 * rs * g1[li + 1] + b1[li + 1];
    y0 = y0 / (1.f + expf(-y0));
    y1 = y1 / (1.f + expf(-y1));
    *(float2*)&first[base] = make_float2(y0, y1);
    *(float2*)&az[base]    = make_float2(dd2 * uuc.x + a2x, dd2 * uuc.y + a2y);
}

// ---------------------------------------------------------------------------
extern "C" void kernel_launch(void* const* d_in, const int* in_sizes, int n_in,
                              void* d_out, int out_size, void* d_ws, size_t ws_size,
                              hipStream_t stream)
{
    const float* u   = (const float*)d_in[0];
    const int*   ei  = (const int*)d_in[1];
    const float* ea  = (const float*)d_in[2];
    const float* xw1 = (const float*)d_in[4];
    const float* xb1 = (const float*)d_in[5];
    const float* xw2 = (const float*)d_in[6];
    const float* xb2 = (const float*)d_in[7];
    const float* zw1 = (const float*)d_in[8];
    const float* zb1 = (const float*)d_in[9];
    const float* zw2 = (const float*)d_in[10];
    const float* zb2 = (const float*)d_in[11];
    const float* weight = (const float*)d_in[12];
    const float* azw = (const float*)d_in[13];
    const float* n1g = (const float*)d_in[14];
    const float* n1b = (const float*)d_in[15];
    const float* n2g = (const float*)d_in[16];
    const float* n2b = (const float*)d_in[17];
    const float* dgp = (const float*)d_in[18];

    int N = in_sizes[0] / HH;
    int E = in_sizes[2] / 8;
    size_t NH = (size_t)N * HH;

    // ws layout (floats first, then ints)
    float* uw2  = (float*)d_ws;
    float* az   = uw2 + NH;
    float4* csr = (float4*)(az + NH);           // E float4s
    int* cnt    = (int*)(csr + E);
    int* off    = cnt + N;                      // N+1
    int* bs     = off + N + 1;                  // up to 256 block sums
    int* cursor = bs + 256;
    int* flag   = cursor + N;
    float* out  = (float*)d_out;

    (void)hipMemsetAsync(cnt, 0, (size_t)N * sizeof(int), stream);

    k_detect<<<1, 64, 0, stream>>>(ei, flag);

    k_hist<<<(E + 255) / 256, 256, 0, stream>>>(ei, flag, cnt, E);

    int nb = (N + 1023) / 1024;
    k_scan_a<<<nb, 256, 0, stream>>>(cnt, off, bs, N);
    k_scan_b<<<1, 256, 0, stream>>>(bs, nb);
    k_scan_c<<<(N + 255) / 256, 256, 0, stream>>>(off, bs, cursor, N, E);

    k_edge_mlp_fill<<<(E + 255) / 256, 256, 0, stream>>>(
        ea, xw1, xb1, xw2, xb2, zw1, zb1, zw2, zb2, ei, flag, cursor, csr, E);

    k_gemm<0><<<(N + 63) / 64, 256, 0, stream>>>(
        u, weight, uw2, nullptr, nullptr, nullptr, nullptr, nullptr, N);

    k_gather<<<(N + 3) / 4, 256, 0, stream>>>(
        csr, off, uw2, u, n1g, n1b, out /*first*/, az, N);

    k_gemm<1><<<(N + 63) / 64, 256, 0, stream>>>(
        az, azw, out, u, out /*first*/, n2g, n2b, dgp, N);
}

// Round 3
// 428.908 us; speedup vs baseline: 13.4264x; 1.3374x over previous
//
#include <hip/hip_runtime.h>

#define HH 128
#define LN_EPS 1e-5f

__device__ __forceinline__ ushort f2bf(float v) {
    unsigned u = __float_as_uint(v);
    unsigned r = (u + 0x7FFFu + ((u >> 16) & 1u)) >> 16;
    return (ushort)r;
}
__device__ __forceinline__ float bf2f(unsigned lo16) { return __uint_as_float(lo16 << 16); }

// ---------------------------------------------------------------------------
__global__ __launch_bounds__(64) void k_detect(const int* __restrict__ ei, int* __restrict__ flag) {
    if (threadIdx.x == 0) {
        int all0 = 1;
        for (int i = 1; i < 128; i += 2) all0 &= (ei[i] == 0);
        *flag = all0;   // 1 -> int64, 0 -> int32
    }
}

// ---------------------------------------------------------------------------
__global__ __launch_bounds__(256) void k_hist(
    const int* __restrict__ ei, const int* __restrict__ flag,
    int* __restrict__ cnt, int E)
{
    int e = blockIdx.x * 256 + threadIdx.x;
    if (e >= E) return;
    int c = (*flag) ? ei[2 * ((size_t)E + e)] : ei[(size_t)E + e];
    atomicAdd(&cnt[c], 1);
}

// ---------------------------------------------------------------------------
__global__ __launch_bounds__(256) void k_scan_a(
    const int* __restrict__ cnt, int* __restrict__ off,
    int* __restrict__ bs, int N)
{
    __shared__ int sm[256];
    int tid = threadIdx.x;
    int base = blockIdx.x * 1024 + tid * 4;
    int v0 = base + 0 < N ? cnt[base + 0] : 0;
    int v1 = base + 1 < N ? cnt[base + 1] : 0;
    int v2 = base + 2 < N ? cnt[base + 2] : 0;
    int v3 = base + 3 < N ? cnt[base + 3] : 0;
    int s = v0 + v1 + v2 + v3;
    sm[tid] = s;
    __syncthreads();
    for (int o = 1; o < 256; o <<= 1) {
        int t = (tid >= o) ? sm[tid - o] : 0;
        __syncthreads();
        sm[tid] += t;
        __syncthreads();
    }
    int excl = sm[tid] - s;
    if (tid == 255) bs[blockIdx.x] = sm[tid];
    if (base + 0 < N) off[base + 0] = excl;
    if (base + 1 < N) off[base + 1] = excl + v0;
    if (base + 2 < N) off[base + 2] = excl + v0 + v1;
    if (base + 3 < N) off[base + 3] = excl + v0 + v1 + v2;
}

__global__ __launch_bounds__(256) void k_scan_b(int* __restrict__ bs, int nb)
{
    __shared__ int sm[256];
    int tid = threadIdx.x;
    int s = tid < nb ? bs[tid] : 0;
    sm[tid] = s;
    __syncthreads();
    for (int o = 1; o < 256; o <<= 1) {
        int t = (tid >= o) ? sm[tid - o] : 0;
        __syncthreads();
        sm[tid] += t;
        __syncthreads();
    }
    if (tid < nb) bs[tid] = sm[tid] - s;
}

__global__ __launch_bounds__(256) void k_scan_c(
    int* __restrict__ off, const int* __restrict__ bs,
    int* __restrict__ cursor, int N, int E)
{
    int i = blockIdx.x * 256 + threadIdx.x;
    if (i >= N) return;
    int o = off[i] + bs[i >> 10];
    off[i] = o;
    cursor[i] = o;
    if (i == 0) off[N] = E;
}

// ---------------------------------------------------------------------------
// Edge MLPs fused with CSR fill. Fast tanh via __expf.
__global__ __launch_bounds__(256) void k_edge_mlp_fill(
    const float* __restrict__ ea,
    const float* __restrict__ xw1, const float* __restrict__ xb1,
    const float* __restrict__ xw2, const float* __restrict__ xb2,
    const float* __restrict__ zw1, const float* __restrict__ zb1,
    const float* __restrict__ zw2, const float* __restrict__ zb2,
    const int* __restrict__ ei, const int* __restrict__ flag,
    int* __restrict__ cursor, float4* __restrict__ csr, int E)
{
    int e = blockIdx.x * 256 + threadIdx.x;
    if (e >= E) return;
    float4 t0 = *(const float4*)&ea[(size_t)e * 8];
    float4 t1 = *(const float4*)&ea[(size_t)e * 8 + 4];
    float a[8] = {t0.x, t0.y, t0.z, t0.w, t1.x, t1.y, t1.z, t1.w};
    float sx = 0.f, sz = 0.f;
#pragma unroll
    for (int j = 0; j < 16; ++j) {
        float hx = xb1[j], hz = zb1[j];
#pragma unroll
        for (int i = 0; i < 8; ++i) {
            hx += a[i] * xw1[i * 16 + j];
            hz += a[i] * zw1[i * 16 + j];
        }
        float tx = __expf(2.f * hx);   // tanh(h) = (e^{2h}-1)/(e^{2h}+1)
        float tz = __expf(2.f * hz);
        sx += (tx - 1.f) / (tx + 1.f) * xw2[j];
        sz += (tz - 1.f) / (tz + 1.f) * zw2[j];
    }
    sx += xb2[0];
    sz += zb2[0];
    int r, c;
    if (*flag) {
        r = ei[2 * (size_t)e];
        c = ei[2 * ((size_t)E + e)];
    } else {
        r = ei[e];
        c = ei[(size_t)E + e];
    }
    int p = atomicAdd(&cursor[c], 1);
    float4 m;
    m.x = __int_as_float(r);
    m.y = 1.0f / (sx + 1e-6f);
    m.z = sz + 1e-6f;
    m.w = 0.f;
    csr[p] = m;
}

// ---------------------------------------------------------------------------
// GEMM: A[64 rows] @ W (128x128), fp32 accumulate, epilogue writes bf16 into
// packed pk rows of 256: HALF=0 -> cols 0..127 = (A@W)^2 ; HALF=1 -> cols
// 128..255 = A@W.
template <int HALF>
__global__ __launch_bounds__(256) void k_gemm(
    const float* __restrict__ A, const float* __restrict__ W,
    ushort* __restrict__ pk, int N)
{
    __shared__ float wl[HH * HH];   // 64 KiB
    int tid = threadIdx.x;
    for (int i = tid; i < HH * HH / 4; i += 256)
        ((float4*)wl)[i] = ((const float4*)W)[i];
    __syncthreads();

    int rg = tid >> 4, cg = tid & 15;
    int r0 = blockIdx.x * 64 + rg * 4;

    float acc[4][8];
#pragma unroll
    for (int rr = 0; rr < 4; ++rr)
#pragma unroll
        for (int j = 0; j < 8; ++j) acc[rr][j] = 0.f;

    size_t rowidx[4];
#pragma unroll
    for (int rr = 0; rr < 4; ++rr) {
        int r = r0 + rr;
        rowidx[rr] = (size_t)(r < N - 1 ? r : N - 1) * HH;
    }

    for (int k4 = 0; k4 < 32; ++k4) {
        float4 a4[4];
#pragma unroll
        for (int rr = 0; rr < 4; ++rr)
            a4[rr] = *(const float4*)&A[rowidx[rr] + k4 * 4];
#pragma unroll
        for (int kk = 0; kk < 4; ++kk) {
            int k = k4 * 4 + kk;
            float4 w0 = *(const float4*)&wl[k * HH + cg * 4];
            float4 w1 = *(const float4*)&wl[k * HH + 64 + cg * 4];
#pragma unroll
            for (int rr = 0; rr < 4; ++rr) {
                float av = ((const float*)&a4[rr])[kk];
                acc[rr][0] += av * w0.x; acc[rr][1] += av * w0.y;
                acc[rr][2] += av * w0.z; acc[rr][3] += av * w0.w;
                acc[rr][4] += av * w1.x; acc[rr][5] += av * w1.y;
                acc[rr][6] += av * w1.z; acc[rr][7] += av * w1.w;
            }
        }
    }

#pragma unroll
    for (int rr = 0; rr < 4; ++rr) {
        int r = r0 + rr;
        if (r >= N) continue;
        ushort4 o0, o1;
        float v;
        v = acc[rr][0]; if (HALF == 0) v *= v; o0.x = f2bf(v);
        v = acc[rr][1]; if (HALF == 0) v *= v; o0.y = f2bf(v);
        v = acc[rr][2]; if (HALF == 0) v *= v; o0.z = f2bf(v);
        v = acc[rr][3]; if (HALF == 0) v *= v; o0.w = f2bf(v);
        v = acc[rr][4]; if (HALF == 0) v *= v; o1.x = f2bf(v);
        v = acc[rr][5]; if (HALF == 0) v *= v; o1.y = f2bf(v);
        v = acc[rr][6]; if (HALF == 0) v *= v; o1.z = f2bf(v);
        v = acc[rr][7]; if (HALF == 0) v *= v; o1.w = f2bf(v);
        size_t b = (size_t)r * 256 + HALF * 128;
        *(ushort4*)&pk[b + cg * 4]      = o0;
        *(ushort4*)&pk[b + 64 + cg * 4] = o1;
    }
}

// ---------------------------------------------------------------------------
// Final gather: one wave per node, 2 edges per step (lane halves), 1x16B load
// per lane per step from packed bf16 rows [uw2(128) | uaz(128)].
// Finishes LN1+silu (first), LN2+silu+1e-6 (azt), and writes
// d_out = clip(u - 0.1*(first + dg*azt_y), +-10).
__global__ __launch_bounds__(256) void k_gather(
    const float4* __restrict__ csr, const int* __restrict__ off,
    const ushort* __restrict__ pk, const float* __restrict__ u,
    const float* __restrict__ g1, const float* __restrict__ b1,
    const float* __restrict__ g2, const float* __restrict__ b2,
    const float* __restrict__ dgp, float* __restrict__ outp, int N)
{
    int wave = threadIdx.x >> 6, lane = threadIdx.x & 63;
    int node = blockIdx.x * 4 + wave;
    if (node >= N) return;
    int p = off[node], end = off[node + 1];

    const bool hi_edge = lane >= 32;       // second edge of each pair
    const int  sub     = lane & 31;        // 16B chunk within 512B row pair
    const bool is_az   = (lane & 16) != 0; // chunk belongs to uaz half

    float acc[8];
#pragma unroll
    for (int j = 0; j < 8; ++j) acc[j] = 0.f;
    float dv = 0.f;

    // 4 edges per iteration (two pair-steps, loads batched)
    while (p + 3 < end) {
        float4 ma0 = csr[p], ma1 = csr[p + 1];
        float4 mb0 = csr[p + 2], mb1 = csr[p + 3];
        float4 mA = hi_edge ? ma1 : ma0;
        float4 mB = hi_edge ? mb1 : mb0;
        float wA = is_az ? mA.z : mA.y;
        float wB = is_az ? mB.z : mB.y;
        int rowA = __float_as_int(mA.x);
        int rowB = __float_as_int(mB.x);
        uint4 qA = *(const uint4*)&pk[(size_t)rowA * 256 + sub * 8];
        uint4 qB = *(const uint4*)&pk[(size_t)rowB * 256 + sub * 8];
        acc[0] += wA * bf2f(qA.x & 0xffffu); acc[1] += wA * bf2f(qA.x >> 16);
        acc[2] += wA * bf2f(qA.y & 0xffffu); acc[3] += wA * bf2f(qA.y >> 16);
        acc[4] += wA * bf2f(qA.z & 0xffffu); acc[5] += wA * bf2f(qA.z >> 16);
        acc[6] += wA * bf2f(qA.w & 0xffffu); acc[7] += wA * bf2f(qA.w >> 16);
        acc[0] += wB * bf2f(qB.x & 0xffffu); acc[1] += wB * bf2f(qB.x >> 16);
        acc[2] += wB * bf2f(qB.y & 0xffffu); acc[3] += wB * bf2f(qB.y >> 16);
        acc[4] += wB * bf2f(qB.z & 0xffffu); acc[5] += wB * bf2f(qB.z >> 16);
        acc[6] += wB * bf2f(qB.w & 0xffffu); acc[7] += wB * bf2f(qB.w >> 16);
        dv += wA + wB;
        p += 4;
    }
    while (p < end) {
        float4 m0 = csr[p];
        float4 m1 = (p + 1 < end) ? csr[p + 1] : m0;
        float4 mm = hi_edge ? m1 : m0;
        float w = is_az ? mm.z : mm.y;
        if (hi_edge && p + 1 >= end) w = 0.f;
        int row = __float_as_int(mm.x);
        uint4 q = *(const uint4*)&pk[(size_t)row * 256 + sub * 8];
        acc[0] += w * bf2f(q.x & 0xffffu); acc[1] += w * bf2f(q.x >> 16);
        acc[2] += w * bf2f(q.y & 0xffffu); acc[3] += w * bf2f(q.y >> 16);
        acc[4] += w * bf2f(q.z & 0xffffu); acc[5] += w * bf2f(q.z >> 16);
        acc[6] += w * bf2f(q.w & 0xffffu); acc[7] += w * bf2f(q.w >> 16);
        dv += w;
        p += 2;
    }

    // combine the two edge-halves
#pragma unroll
    for (int j = 0; j < 8; ++j) acc[j] += __shfl_xor(acc[j], 32);
    dv += __shfl_xor(dv, 32);
    if (dv == 0.f) dv = 1.f;

    // diagonal term from own row
    uint4 qc = *(const uint4*)&pk[(size_t)node * 256 + sub * 8];
    float x[8];
    x[0] = dv * bf2f(qc.x & 0xffffu) + acc[0]; x[1] = dv * bf2f(qc.x >> 16) + acc[1];
    x[2] = dv * bf2f(qc.y & 0xffffu) + acc[2]; x[3] = dv * bf2f(qc.y >> 16) + acc[3];
    x[4] = dv * bf2f(qc.z & 0xffffu) + acc[4]; x[5] = dv * bf2f(qc.z >> 16) + acc[5];
    x[6] = dv * bf2f(qc.w & 0xffffu) + acc[6]; x[7] = dv * bf2f(qc.w >> 16) + acc[7];

    // LayerNorm within each 16-lane group (group holds all 128 cols)
    float s = 0.f;
#pragma unroll
    for (int j = 0; j < 8; ++j) s += x[j];
    s += __shfl_xor(s, 1, 16); s += __shfl_xor(s, 2, 16);
    s += __shfl_xor(s, 4, 16); s += __shfl_xor(s, 8, 16);
    float mu = s * (1.f / 128.f);
    float s2 = 0.f;
#pragma unroll
    for (int j = 0; j < 8; ++j) { x[j] -= mu; s2 += x[j] * x[j]; }
    s2 += __shfl_xor(s2, 1, 16); s2 += __shfl_xor(s2, 2, 16);
    s2 += __shfl_xor(s2, 4, 16); s2 += __shfl_xor(s2, 8, 16);
    float rs = rsqrtf(s2 * (1.f / 128.f) + LN_EPS);

    int c8 = (sub & 15) * 8;
    const float* gp = is_az ? g2 : g1;
    const float* bp = is_az ? b2 : b1;
    float4 gv0 = *(const float4*)&gp[c8];
    float4 gv1 = *(const float4*)&gp[c8 + 4];
    float4 bv0 = *(const float4*)&bp[c8];
    float4 bv1 = *(const float4*)&bp[c8 + 4];
    float gA[8] = {gv0.x, gv0.y, gv0.z, gv0.w, gv1.x, gv1.y, gv1.z, gv1.w};
    float bA[8] = {bv0.x, bv0.y, bv0.z, bv0.w, bv1.x, bv1.y, bv1.z, bv1.w};

    float y[8];
#pragma unroll
    for (int j = 0; j < 8; ++j) {
        float v = x[j] * rs * gA[j] + bA[j];
        v = v / (1.f + __expf(-v));          // silu
        if (is_az) v += 1e-6f;               // azt path epsilon
        y[j] = v;
    }

    // bring azt-y down to the first-lanes (xor 16 swaps the halves)
    float dg = *dgp;
    float yz[8];
#pragma unroll
    for (int j = 0; j < 8; ++j) yz[j] = __shfl_xor(y[j], 16);

    if (lane < 16) {
        size_t ub = (size_t)node * HH + c8;
        float4 u0 = *(const float4*)&u[ub];
        float4 u1 = *(const float4*)&u[ub + 4];
        float o[8];
        o[0] = u0.x; o[1] = u0.y; o[2] = u0.z; o[3] = u0.w;
        o[4] = u1.x; o[5] = u1.y; o[6] = u1.z; o[7] = u1.w;
#pragma unroll
        for (int j = 0; j < 8; ++j) {
            float v = o[j] - 0.1f * (y[j] + dg * yz[j]);
            o[j] = fminf(fmaxf(v, -10.f), 10.f);
        }
        float4 w0 = make_float4(o[0], o[1], o[2], o[3]);
        float4 w1 = make_float4(o[4], o[5], o[6], o[7]);
        *(float4*)&outp[ub]     = w0;
        *(float4*)&outp[ub + 4] = w1;
    }
}

// ---------------------------------------------------------------------------
extern "C" void kernel_launch(void* const* d_in, const int* in_sizes, int n_in,
                              void* d_out, int out_size, void* d_ws, size_t ws_size,
                              hipStream_t stream)
{
    const float* u   = (const float*)d_in[0];
    const int*   ei  = (const int*)d_in[1];
    const float* ea  = (const float*)d_in[2];
    const float* xw1 = (const float*)d_in[4];
    const float* xb1 = (const float*)d_in[5];
    const float* xw2 = (const float*)d_in[6];
    const float* xb2 = (const float*)d_in[7];
    const float* zw1 = (const float*)d_in[8];
    const float* zb1 = (const float*)d_in[9];
    const float* zw2 = (const float*)d_in[10];
    const float* zb2 = (const float*)d_in[11];
    const float* weight = (const float*)d_in[12];
    const float* azw = (const float*)d_in[13];
    const float* n1g = (const float*)d_in[14];
    const float* n1b = (const float*)d_in[15];
    const float* n2g = (const float*)d_in[16];
    const float* n2b = (const float*)d_in[17];
    const float* dgp = (const float*)d_in[18];

    int N = in_sizes[0] / HH;
    int E = in_sizes[2] / 8;

    // ws layout
    ushort* pk  = (ushort*)d_ws;                 // N * 256 bf16
    float4* csr = (float4*)(pk + (size_t)N * 256);
    int* cnt    = (int*)(csr + E);
    int* off    = cnt + N;                       // N+1
    int* bs     = off + N + 1;
    int* cursor = bs + 256;
    int* flag   = cursor + N;

    (void)hipMemsetAsync(cnt, 0, (size_t)N * sizeof(int), stream);

    k_detect<<<1, 64, 0, stream>>>(ei, flag);

    k_hist<<<(E + 255) / 256, 256, 0, stream>>>(ei, flag, cnt, E);

    int nb = (N + 1023) / 1024;
    k_scan_a<<<nb, 256, 0, stream>>>(cnt, off, bs, N);
    k_scan_b<<<1, 256, 0, stream>>>(bs, nb);
    k_scan_c<<<(N + 255) / 256, 256, 0, stream>>>(off, bs, cursor, N, E);

    k_edge_mlp_fill<<<(E + 255) / 256, 256, 0, stream>>>(
        ea, xw1, xb1, xw2, xb2, zw1, zb1, zw2, zb2, ei, flag, cursor, csr, E);

    k_gemm<0><<<(N + 63) / 64, 256, 0, stream>>>(u, weight, pk, N);
    k_gemm<1><<<(N + 63) / 64, 256, 0, stream>>>(u, azw, pk, N);

    k_gather<<<(N + 3) / 4, 256, 0, stream>>>(
        csr, off, pk, u, n1g, n1b, n2g, n2b, dgp, (float*)d_out, N);
}

// Round 4
// 355.409 us; speedup vs baseline: 16.2029x; 1.2068x over previous
//
#include <hip/hip_runtime.h>

#define HH 128
#define LN_EPS 1e-5f

typedef __attribute__((ext_vector_type(8))) short bfrag8;
typedef __attribute__((ext_vector_type(4))) float f32x4;

__device__ __forceinline__ ushort f2bf(float v) {
    unsigned u = __float_as_uint(v);
    unsigned r = (u + 0x7FFFu + ((u >> 16) & 1u)) >> 16;
    return (ushort)r;
}
__device__ __forceinline__ float bf2f(unsigned lo16) { return __uint_as_float(lo16 << 16); }

// ---------------------------------------------------------------------------
__global__ __launch_bounds__(64) void k_detect(const int* __restrict__ ei, int* __restrict__ flag) {
    if (threadIdx.x == 0) {
        int all0 = 1;
        for (int i = 1; i < 128; i += 2) all0 &= (ei[i] == 0);
        *flag = all0;   // 1 -> int64, 0 -> int32
    }
}

// ---------------------------------------------------------------------------
// Histogram, 4 edges per thread, vector loads.
__global__ __launch_bounds__(256) void k_hist(
    const int* __restrict__ ei, const int* __restrict__ flag,
    int* __restrict__ cnt, int E)
{
    int e0 = (blockIdx.x * 256 + threadIdx.x) * 4;
    if (e0 >= E) return;
    int c[4];
    int nv = min(4, E - e0);
    if (*flag) {
        if (nv == 4) {
            int4 a = *(const int4*)&ei[2 * ((size_t)E + e0)];
            int4 b = *(const int4*)&ei[2 * ((size_t)E + e0) + 4];
            c[0] = a.x; c[1] = a.z; c[2] = b.x; c[3] = b.z;
        } else {
            for (int i = 0; i < nv; ++i) c[i] = ei[2 * ((size_t)E + e0 + i)];
        }
    } else {
        if (nv == 4) {
            int4 a = *(const int4*)&ei[(size_t)E + e0];
            c[0] = a.x; c[1] = a.y; c[2] = a.z; c[3] = a.w;
        } else {
            for (int i = 0; i < nv; ++i) c[i] = ei[(size_t)E + e0 + i];
        }
    }
    for (int i = 0; i < nv; ++i) atomicAdd(&cnt[c[i]], 1);
}

// ---------------------------------------------------------------------------
__global__ __launch_bounds__(256) void k_scan_a(
    const int* __restrict__ cnt, int* __restrict__ off,
    int* __restrict__ bs, int N)
{
    __shared__ int sm[256];
    int tid = threadIdx.x;
    int base = blockIdx.x * 1024 + tid * 4;
    int v0 = base + 0 < N ? cnt[base + 0] : 0;
    int v1 = base + 1 < N ? cnt[base + 1] : 0;
    int v2 = base + 2 < N ? cnt[base + 2] : 0;
    int v3 = base + 3 < N ? cnt[base + 3] : 0;
    int s = v0 + v1 + v2 + v3;
    sm[tid] = s;
    __syncthreads();
    for (int o = 1; o < 256; o <<= 1) {
        int t = (tid >= o) ? sm[tid - o] : 0;
        __syncthreads();
        sm[tid] += t;
        __syncthreads();
    }
    int excl = sm[tid] - s;
    if (tid == 255) bs[blockIdx.x] = sm[tid];
    if (base + 0 < N) off[base + 0] = excl;
    if (base + 1 < N) off[base + 1] = excl + v0;
    if (base + 2 < N) off[base + 2] = excl + v0 + v1;
    if (base + 3 < N) off[base + 3] = excl + v0 + v1 + v2;
}

__global__ __launch_bounds__(256) void k_scan_b(int* __restrict__ bs, int nb)
{
    __shared__ int sm[256];
    int tid = threadIdx.x;
    int s = tid < nb ? bs[tid] : 0;
    sm[tid] = s;
    __syncthreads();
    for (int o = 1; o < 256; o <<= 1) {
        int t = (tid >= o) ? sm[tid - o] : 0;
        __syncthreads();
        sm[tid] += t;
        __syncthreads();
    }
    if (tid < nb) bs[tid] = sm[tid] - s;
}

__global__ __launch_bounds__(256) void k_scan_c(
    int* __restrict__ off, const int* __restrict__ bs,
    int* __restrict__ cursor, int N, int E)
{
    int i = blockIdx.x * 256 + threadIdx.x;
    if (i >= N) return;
    int o = off[i] + bs[i >> 10];
    off[i] = o;
    cursor[i] = o;
    if (i == 0) off[N] = E;
}

// ---------------------------------------------------------------------------
// Edge MLPs fused with CSR fill. 8-byte entries {row; bf16 vx; bf16 vz}.
__global__ __launch_bounds__(256) void k_edge_mlp_fill(
    const float* __restrict__ ea,
    const float* __restrict__ xw1, const float* __restrict__ xb1,
    const float* __restrict__ xw2, const float* __restrict__ xb2,
    const float* __restrict__ zw1, const float* __restrict__ zb1,
    const float* __restrict__ zw2, const float* __restrict__ zb2,
    const int* __restrict__ ei, const int* __restrict__ flag,
    int* __restrict__ cursor, uint2* __restrict__ csr, int E)
{
    int e = blockIdx.x * 256 + threadIdx.x;
    if (e >= E) return;
    float4 t0 = *(const float4*)&ea[(size_t)e * 8];
    float4 t1 = *(const float4*)&ea[(size_t)e * 8 + 4];
    float a[8] = {t0.x, t0.y, t0.z, t0.w, t1.x, t1.y, t1.z, t1.w};
    float sx = 0.f, sz = 0.f;
#pragma unroll
    for (int j = 0; j < 16; ++j) {
        float hx = xb1[j], hz = zb1[j];
#pragma unroll
        for (int i = 0; i < 8; ++i) {
            hx += a[i] * xw1[i * 16 + j];
            hz += a[i] * zw1[i * 16 + j];
        }
        float tx = __expf(2.f * hx);   // tanh(h) = (e^{2h}-1)/(e^{2h}+1)
        float tz = __expf(2.f * hz);
        sx += __fdividef(tx - 1.f, tx + 1.f) * xw2[j];
        sz += __fdividef(tz - 1.f, tz + 1.f) * zw2[j];
    }
    sx += xb2[0];
    sz += zb2[0];
    int r, c;
    if (*flag) {
        r = ei[2 * (size_t)e];
        c = ei[2 * ((size_t)E + e)];
    } else {
        r = ei[e];
        c = ei[(size_t)E + e];
    }
    int p = atomicAdd(&cursor[c], 1);
    unsigned wx = f2bf(1.0f / (sx + 1e-6f));
    unsigned wz = f2bf(sz + 1e-6f);
    uint2 m;
    m.x = (unsigned)r;
    m.y = wx | (wz << 16);
    csr[p] = m;
}

// ---------------------------------------------------------------------------
// Fused dual GEMM via MFMA bf16: pk[r][0:128] = (u@weight)^2 (bf16),
// pk[r][128:256] = u@az_weight (bf16).  128 rows per block, 4 waves.
// Both weights staged transposed bf16 in LDS: WT[n][k], pitch 136.
#define WPITCH 136
__global__ __launch_bounds__(256) void k_gemm_fused(
    const float* __restrict__ A, const float* __restrict__ W0,
    const float* __restrict__ W1, ushort* __restrict__ pk, int N)
{
    __shared__ ushort wt[256 * WPITCH];   // ~69.6 KiB

    int tid = threadIdx.x;
    // stage: 4x4 tiles, 2048 tiles total, 8 per thread
    for (int it = 0; it < 8; ++it) {
        int tile = tid + it * 256;
        int kt = tile & 31, nt = tile >> 5;      // k0 = kt*4, n0 = nt*4
        int k0 = kt * 4, n0 = nt * 4;
        const float* src = (n0 < HH) ? W0 : W1;
        int cn = n0 & (HH - 1);
        float4 r0 = *(const float4*)&src[(k0 + 0) * HH + cn];
        float4 r1 = *(const float4*)&src[(k0 + 1) * HH + cn];
        float4 r2 = *(const float4*)&src[(k0 + 2) * HH + cn];
        float4 r3 = *(const float4*)&src[(k0 + 3) * HH + cn];
        const float* rr[4] = {(const float*)&r0, (const float*)&r1,
                              (const float*)&r2, (const float*)&r3};
#pragma unroll
        for (int j = 0; j < 4; ++j) {
            ushort4 v;
            v.x = f2bf(rr[0][j]); v.y = f2bf(rr[1][j]);
            v.z = f2bf(rr[2][j]); v.w = f2bf(rr[3][j]);
            *(ushort4*)&wt[(n0 + j) * WPITCH + k0] = v;
        }
    }
    __syncthreads();

    int w = tid >> 6, lane = tid & 63;
    int lr = lane & 15, lg = lane >> 4;

    f32x4 acc[2][16];
#pragma unroll
    for (int rt = 0; rt < 2; ++rt)
#pragma unroll
        for (int ct = 0; ct < 16; ++ct)
            acc[rt][ct] = (f32x4){0.f, 0.f, 0.f, 0.f};

    int rbase = blockIdx.x * 128 + w * 32 + lr;
    int ra0 = min(rbase,      N - 1);
    int ra1 = min(rbase + 16, N - 1);

    for (int ks = 0; ks < 4; ++ks) {
        int kofs = ks * 32 + lg * 8;
        bfrag8 afr[2];
#pragma unroll
        for (int rt = 0; rt < 2; ++rt) {
            const float* ap = &A[(size_t)(rt ? ra1 : ra0) * HH + kofs];
            float4 f0 = *(const float4*)ap;
            float4 f1 = *(const float4*)(ap + 4);
            bfrag8 fr;
            fr[0] = (short)f2bf(f0.x); fr[1] = (short)f2bf(f0.y);
            fr[2] = (short)f2bf(f0.z); fr[3] = (short)f2bf(f0.w);
            fr[4] = (short)f2bf(f1.x); fr[5] = (short)f2bf(f1.y);
            fr[6] = (short)f2bf(f1.z); fr[7] = (short)f2bf(f1.w);
            afr[rt] = fr;
        }
#pragma unroll
        for (int ct = 0; ct < 16; ++ct) {
            bfrag8 bfr = *(const bfrag8*)&wt[(ct * 16 + lr) * WPITCH + kofs];
            acc[0][ct] = __builtin_amdgcn_mfma_f32_16x16x32_bf16(afr[0], bfr, acc[0][ct], 0, 0, 0);
            acc[1][ct] = __builtin_amdgcn_mfma_f32_16x16x32_bf16(afr[1], bfr, acc[1][ct], 0, 0, 0);
        }
    }

    // epilogue: C/D layout col = lane&15, row = (lane>>4)*4 + reg
#pragma unroll
    for (int rt = 0; rt < 2; ++rt) {
#pragma unroll
        for (int ct = 0; ct < 16; ++ct) {
            int C = ct * 16 + lr;
            int R0 = blockIdx.x * 128 + w * 32 + rt * 16 + lg * 4;
#pragma unroll
            for (int reg = 0; reg < 4; ++reg) {
                int R = R0 + reg;
                if (R < N) {
                    float v = acc[rt][ct][reg];
                    if (C < HH) v *= v;
                    pk[(size_t)R * 256 + C] = f2bf(v);
                }
            }
        }
    }
}

// ---------------------------------------------------------------------------
// Final gather: one wave per node, 2 edges per step (lane halves), 1x16B load
// per lane per step from packed bf16 rows [uw2(128) | uaz(128)].
__global__ __launch_bounds__(256) void k_gather(
    const uint2* __restrict__ csr, const int* __restrict__ off,
    const ushort* __restrict__ pk, const float* __restrict__ u,
    const float* __restrict__ g1, const float* __restrict__ b1,
    const float* __restrict__ g2, const float* __restrict__ b2,
    const float* __restrict__ dgp, float* __restrict__ outp, int N)
{
    int wave = threadIdx.x >> 6, lane = threadIdx.x & 63;
    int node = blockIdx.x * 4 + wave;
    if (node >= N) return;
    int p = off[node], end = off[node + 1];

    const bool hi_edge = lane >= 32;
    const int  sub     = lane & 31;
    const bool is_az   = (lane & 16) != 0;

    float acc[8];
#pragma unroll
    for (int j = 0; j < 8; ++j) acc[j] = 0.f;
    float dv = 0.f;

    while (p + 3 < end) {
        uint2 ma0 = csr[p], ma1 = csr[p + 1];
        uint2 mb0 = csr[p + 2], mb1 = csr[p + 3];
        uint2 mA = hi_edge ? ma1 : ma0;
        uint2 mB = hi_edge ? mb1 : mb0;
        float wA = bf2f(is_az ? (mA.y >> 16) : (mA.y & 0xffffu));
        float wB = bf2f(is_az ? (mB.y >> 16) : (mB.y & 0xffffu));
        uint4 qA = *(const uint4*)&pk[(size_t)mA.x * 256 + sub * 8];
        uint4 qB = *(const uint4*)&pk[(size_t)mB.x * 256 + sub * 8];
        acc[0] += wA * bf2f(qA.x & 0xffffu); acc[1] += wA * bf2f(qA.x >> 16);
        acc[2] += wA * bf2f(qA.y & 0xffffu); acc[3] += wA * bf2f(qA.y >> 16);
        acc[4] += wA * bf2f(qA.z & 0xffffu); acc[5] += wA * bf2f(qA.z >> 16);
        acc[6] += wA * bf2f(qA.w & 0xffffu); acc[7] += wA * bf2f(qA.w >> 16);
        acc[0] += wB * bf2f(qB.x & 0xffffu); acc[1] += wB * bf2f(qB.x >> 16);
        acc[2] += wB * bf2f(qB.y & 0xffffu); acc[3] += wB * bf2f(qB.y >> 16);
        acc[4] += wB * bf2f(qB.z & 0xffffu); acc[5] += wB * bf2f(qB.z >> 16);
        acc[6] += wB * bf2f(qB.w & 0xffffu); acc[7] += wB * bf2f(qB.w >> 16);
        dv += wA + wB;
        p += 4;
    }
    while (p < end) {
        uint2 m0 = csr[p];
        uint2 m1 = (p + 1 < end) ? csr[p + 1] : m0;
        uint2 mm = hi_edge ? m1 : m0;
        float wv = bf2f(is_az ? (mm.y >> 16) : (mm.y & 0xffffu));
        if (hi_edge && p + 1 >= end) wv = 0.f;
        uint4 q = *(const uint4*)&pk[(size_t)mm.x * 256 + sub * 8];
        acc[0] += wv * bf2f(q.x & 0xffffu); acc[1] += wv * bf2f(q.x >> 16);
        acc[2] += wv * bf2f(q.y & 0xffffu); acc[3] += wv * bf2f(q.y >> 16);
        acc[4] += wv * bf2f(q.z & 0xffffu); acc[5] += wv * bf2f(q.z >> 16);
        acc[6] += wv * bf2f(q.w & 0xffffu); acc[7] += wv * bf2f(q.w >> 16);
        dv += wv;
        p += 2;
    }

#pragma unroll
    for (int j = 0; j < 8; ++j) acc[j] += __shfl_xor(acc[j], 32);
    dv += __shfl_xor(dv, 32);
    if (dv == 0.f) dv = 1.f;

    uint4 qc = *(const uint4*)&pk[(size_t)node * 256 + sub * 8];
    float x[8];
    x[0] = dv * bf2f(qc.x & 0xffffu) + acc[0]; x[1] = dv * bf2f(qc.x >> 16) + acc[1];
    x[2] = dv * bf2f(qc.y & 0xffffu) + acc[2]; x[3] = dv * bf2f(qc.y >> 16) + acc[3];
    x[4] = dv * bf2f(qc.z & 0xffffu) + acc[4]; x[5] = dv * bf2f(qc.z >> 16) + acc[5];
    x[6] = dv * bf2f(qc.w & 0xffffu) + acc[6]; x[7] = dv * bf2f(qc.w >> 16) + acc[7];

    float s = 0.f;
#pragma unroll
    for (int j = 0; j < 8; ++j) s += x[j];
    s += __shfl_xor(s, 1, 16); s += __shfl_xor(s, 2, 16);
    s += __shfl_xor(s, 4, 16); s += __shfl_xor(s, 8, 16);
    float mu = s * (1.f / 128.f);
    float s2 = 0.f;
#pragma unroll
    for (int j = 0; j < 8; ++j) { x[j] -= mu; s2 += x[j] * x[j]; }
    s2 += __shfl_xor(s2, 1, 16); s2 += __shfl_xor(s2, 2, 16);
    s2 += __shfl_xor(s2, 4, 16); s2 += __shfl_xor(s2, 8, 16);
    float rs = rsqrtf(s2 * (1.f / 128.f) + LN_EPS);

    int c8 = (sub & 15) * 8;
    const float* gp = is_az ? g2 : g1;
    const float* bp = is_az ? b2 : b1;
    float4 gv0 = *(const float4*)&gp[c8];
    float4 gv1 = *(const float4*)&gp[c8 + 4];
    float4 bv0 = *(const float4*)&bp[c8];
    float4 bv1 = *(const float4*)&bp[c8 + 4];
    float gA[8] = {gv0.x, gv0.y, gv0.z, gv0.w, gv1.x, gv1.y, gv1.z, gv1.w};
    float bA[8] = {bv0.x, bv0.y, bv0.z, bv0.w, bv1.x, bv1.y, bv1.z, bv1.w};

    float y[8];
#pragma unroll
    for (int j = 0; j < 8; ++j) {
        float v = x[j] * rs * gA[j] + bA[j];
        v = v / (1.f + __expf(-v));
        if (is_az) v += 1e-6f;
        y[j] = v;
    }

    float dg = *dgp;
    float yz[8];
#pragma unroll
    for (int j = 0; j < 8; ++j) yz[j] = __shfl_xor(y[j], 16);

    if (lane < 16) {
        size_t ub = (size_t)node * HH + c8;
        float4 u0 = *(const float4*)&u[ub];
        float4 u1 = *(const float4*)&u[ub + 4];
        float o[8];
        o[0] = u0.x; o[1] = u0.y; o[2] = u0.z; o[3] = u0.w;
        o[4] = u1.x; o[5] = u1.y; o[6] = u1.z; o[7] = u1.w;
#pragma unroll
        for (int j = 0; j < 8; ++j) {
            float v = o[j] - 0.1f * (y[j] + dg * yz[j]);
            o[j] = fminf(fmaxf(v, -10.f), 10.f);
        }
        *(float4*)&outp[ub]     = make_float4(o[0], o[1], o[2], o[3]);
        *(float4*)&outp[ub + 4] = make_float4(o[4], o[5], o[6], o[7]);
    }
}

// ---------------------------------------------------------------------------
extern "C" void kernel_launch(void* const* d_in, const int* in_sizes, int n_in,
                              void* d_out, int out_size, void* d_ws, size_t ws_size,
                              hipStream_t stream)
{
    const float* u   = (const float*)d_in[0];
    const int*   ei  = (const int*)d_in[1];
    const float* ea  = (const float*)d_in[2];
    const float* xw1 = (const float*)d_in[4];
    const float* xb1 = (const float*)d_in[5];
    const float* xw2 = (const float*)d_in[6];
    const float* xb2 = (const float*)d_in[7];
    const float* zw1 = (const float*)d_in[8];
    const float* zb1 = (const float*)d_in[9];
    const float* zw2 = (const float*)d_in[10];
    const float* zb2 = (const float*)d_in[11];
    const float* weight = (const float*)d_in[12];
    const float* azw = (const float*)d_in[13];
    const float* n1g = (const float*)d_in[14];
    const float* n1b = (const float*)d_in[15];
    const float* n2g = (const float*)d_in[16];
    const float* n2b = (const float*)d_in[17];
    const float* dgp = (const float*)d_in[18];

    int N = in_sizes[0] / HH;
    int E = in_sizes[2] / 8;

    // ws layout
    ushort* pk  = (ushort*)d_ws;                 // N * 256 bf16
    uint2* csr  = (uint2*)(pk + (size_t)N * 256);
    int* cnt    = (int*)(csr + E);
    int* off    = cnt + N;                       // N+1
    int* bs     = off + N + 1;
    int* cursor = bs + 256;
    int* flag   = cursor + N;

    (void)hipMemsetAsync(cnt, 0, (size_t)N * sizeof(int), stream);

    k_detect<<<1, 64, 0, stream>>>(ei, flag);

    k_hist<<<(E / 4 + 255) / 256, 256, 0, stream>>>(ei, flag, cnt, E);

    int nb = (N + 1023) / 1024;
    k_scan_a<<<nb, 256, 0, stream>>>(cnt, off, bs, N);
    k_scan_b<<<1, 256, 0, stream>>>(bs, nb);
    k_scan_c<<<(N + 255) / 256, 256, 0, stream>>>(off, bs, cursor, N, E);

    k_edge_mlp_fill<<<(E + 255) / 256, 256, 0, stream>>>(
        ea, xw1, xb1, xw2, xb2, zw1, zb1, zw2, zb2, ei, flag, cursor, csr, E);

    k_gemm_fused<<<(N + 127) / 128, 256, 0, stream>>>(u, weight, azw, pk, N);

    k_gather<<<(N + 3) / 4, 256, 0, stream>>>(
        csr, off, pk, u, n1g, n1b, n2g, n2b, dgp, (float*)d_out, N);
}